// Round 1
// baseline (9437.032 us; speedup 1.0000x reference)
//
#include <hip/hip_runtime.h>

#define N_NODES 50000
#define N_EDGES 640000
#define HID 128
#define N_LAYERS 4

__device__ __forceinline__ float silu_f(float x) {
    return x / (1.0f + __expf(-x));
}

// h[i,c] = sum_k nodes[i,k]*emb_w[k,c] + emb_b[c]
__global__ void k_embed(const float* __restrict__ nodes, const float* __restrict__ ew,
                        const float* __restrict__ eb, float* __restrict__ h) {
    int idx = blockIdx.x * 256 + threadIdx.x;
    if (idx >= N_NODES * HID) return;
    int i = idx >> 7, c = idx & 127;
    float n0 = nodes[i * 3 + 0], n1 = nodes[i * 3 + 1], n2 = nodes[i * 3 + 2];
    h[idx] = n0 * ew[c] + n1 * ew[HID + c] + n2 * ew[2 * HID + c] + eb[c];
}

// out[M,128] = act(X[M,K] @ W[K,128] + bias), X = [X1 | X2] (each row-stride 128)
// BM=64, BN=128, BK=32, 256 threads, each thread 8x4 outputs.
__global__ __launch_bounds__(256) void k_gemm(
    const float* __restrict__ X1, const float* __restrict__ X2,
    const float* __restrict__ W, const float* __restrict__ bias,
    float* __restrict__ out, int M, int K, int do_silu) {
    __shared__ float Xs[32][68];
    __shared__ float Ws[32][128];
    const int t = threadIdx.x;
    const int m0 = blockIdx.x * 64;
    const int r0 = (t >> 5) * 8;
    const int c0 = (t & 31) * 4;
    const int lr = t >> 3;          // 0..31
    const int lk = (t & 7) * 4;     // 0..28
    float acc[8][4] = {};

    for (int kk = 0; kk < K; kk += 32) {
        const float* Xp = (X2 != nullptr && kk >= 128) ? X2 : X1;
        int kb = kk & 127;
#pragma unroll
        for (int hh = 0; hh < 2; ++hh) {
            int r = lr + hh * 32;
            int gm = m0 + r; if (gm >= M) gm = M - 1;
            float4 v = *(const float4*)&Xp[(size_t)gm * 128 + kb + lk];
            Xs[lk + 0][r] = v.x; Xs[lk + 1][r] = v.y;
            Xs[lk + 2][r] = v.z; Xs[lk + 3][r] = v.w;
        }
#pragma unroll
        for (int i = 0; i < 4; ++i) {
            int idx = t + i * 256;       // float4 index 0..1023
            int wk = idx >> 5;
            int wc = (idx & 31) * 4;
            *(float4*)&Ws[wk][wc] = *(const float4*)&W[(size_t)(kk + wk) * 128 + wc];
        }
        __syncthreads();
#pragma unroll
        for (int k = 0; k < 32; ++k) {
            float xr[8], wr[4];
            *(float4*)&xr[0] = *(const float4*)&Xs[k][r0];
            *(float4*)&xr[4] = *(const float4*)&Xs[k][r0 + 4];
            *(float4*)&wr[0] = *(const float4*)&Ws[k][c0];
#pragma unroll
            for (int i = 0; i < 8; ++i)
#pragma unroll
                for (int j = 0; j < 4; ++j)
                    acc[i][j] += xr[i] * wr[j];
        }
        __syncthreads();
    }
    float bv[4] = {0.f, 0.f, 0.f, 0.f};
    if (bias) *(float4*)bv = *(const float4*)&bias[c0];
#pragma unroll
    for (int i = 0; i < 8; ++i) {
        int gm = m0 + r0 + i;
        if (gm < M) {
            float o[4];
#pragma unroll
            for (int j = 0; j < 4; ++j) {
                float v = acc[i][j] + bv[j];
                o[j] = do_silu ? silu_f(v) : v;
            }
            *(float4*)&out[(size_t)gm * 128 + c0] = *(float4*)o;
        }
    }
}

// Edge kernel: per edge e: m1 = silu(A[row]+B[col]+ea*w1last); m = silu(m1@W2+b2);
// atomicAdd into agg[row]. Tile = 64 edges, 512 threads, W2 in LDS, pipelined gathers.
__global__ __launch_bounds__(512) void k_edge(
    const float* __restrict__ A, const float* __restrict__ Bm,
    const float* __restrict__ w1last, const float* __restrict__ b2,
    const float* __restrict__ W2, const int* __restrict__ row,
    const int* __restrict__ col, const float* __restrict__ ea,
    float* __restrict__ agg) {
    __shared__ float W2s[128 * 128];
    __shared__ float m1s[64][132];
    __shared__ int rows_s[64];
    const int t = threadIdx.x;
    for (int i = t; i < 4096; i += 512)
        ((float4*)W2s)[i] = ((const float4*)W2)[i];

    const int elA = t >> 3;          // 0..63
    const int cA = (t & 7) * 16;     // 0..112
    const int p = t >> 4;            // 0..31
    const int cB = (t & 15) * 8;     // 0..120

    float w1l[16];
#pragma unroll
    for (int j4 = 0; j4 < 4; ++j4)
        *(float4*)&w1l[j4 * 4] = *(const float4*)&w1last[cA + j4 * 4];
    float b2v[8];
    *(float4*)&b2v[0] = *(const float4*)&b2[cB];
    *(float4*)&b2v[4] = *(const float4*)&b2[cB + 4];

    const int stride = gridDim.x * 64;
    float av[16], bv[16], eav = 0.f;
    int r_ = 0;

    auto load_tile = [&](int bs) {
        int e = bs + elA;
        int r = row[e], c = col[e];
        eav = ea[e]; r_ = r;
        const float* Ap = A + (size_t)r * 128 + cA;
        const float* Bp = Bm + (size_t)c * 128 + cA;
#pragma unroll
        for (int j = 0; j < 4; ++j) {
            *(float4*)&av[j * 4] = *(const float4*)&Ap[j * 4];
            *(float4*)&bv[j * 4] = *(const float4*)&Bp[j * 4];
        }
    };

    int base0 = blockIdx.x * 64;
    if (base0 < N_EDGES) load_tile(base0);

    for (int bs = base0; bs < N_EDGES; bs += stride) {
        __syncthreads();   // m1s free (previous GEMM done)
        {
            float m1v[16];
#pragma unroll
            for (int j = 0; j < 16; ++j) {
                float x = av[j] + bv[j] + eav * w1l[j];
                m1v[j] = silu_f(x);
            }
#pragma unroll
            for (int j4 = 0; j4 < 4; ++j4)
                *(float4*)&m1s[elA][cA + j4 * 4] = *(float4*)&m1v[j4 * 4];
            if ((t & 7) == 0) rows_s[elA] = r_;
        }
        __syncthreads();   // m1s ready
        int nb = bs + stride;
        if (nb < N_EDGES) load_tile(nb);   // prefetch: latency hides under GEMM

        float acc0[8] = {}, acc1[8] = {};
#pragma unroll 8
        for (int k = 0; k < 128; k += 4) {
            float m0a[4], m1a[4];
            *(float4*)m0a = *(const float4*)&m1s[2 * p][k];
            *(float4*)m1a = *(const float4*)&m1s[2 * p + 1][k];
#pragma unroll
            for (int j = 0; j < 4; ++j) {
                float wv[8];
                *(float4*)&wv[0] = *(const float4*)&W2s[(k + j) * 128 + cB];
                *(float4*)&wv[4] = *(const float4*)&W2s[(k + j) * 128 + cB + 4];
#pragma unroll
                for (int q = 0; q < 8; ++q) {
                    acc0[q] += m0a[j] * wv[q];
                    acc1[q] += m1a[j] * wv[q];
                }
            }
        }
        int r0e = rows_s[2 * p], r1e = rows_s[2 * p + 1];
        float* g0 = agg + (size_t)r0e * 128 + cB;
        float* g1 = agg + (size_t)r1e * 128 + cB;
#pragma unroll
        for (int q = 0; q < 8; ++q) {
            float x0 = acc0[q] + b2v[q];
            float x1 = acc1[q] + b2v[q];
            atomicAdd(&g0[q], silu_f(x0));
            atomicAdd(&g1[q], silu_f(x1));
        }
    }
}

// out[i,0..2] = u[i,:] @ dec_w2 + dec_b2
__global__ void k_dec2(const float* __restrict__ u, const float* __restrict__ w,
                       const float* __restrict__ b, float* __restrict__ out) {
    int i = blockIdx.x * 256 + threadIdx.x;
    if (i >= N_NODES) return;
    float a0 = b[0], a1 = b[1], a2 = b[2];
    const float4* u4 = (const float4*)(u + (size_t)i * 128);
#pragma unroll
    for (int k4 = 0; k4 < 32; ++k4) {
        float4 v = u4[k4];
        int k = k4 * 4;
        a0 += v.x * w[k * 3 + 0] + v.y * w[(k + 1) * 3 + 0] + v.z * w[(k + 2) * 3 + 0] + v.w * w[(k + 3) * 3 + 0];
        a1 += v.x * w[k * 3 + 1] + v.y * w[(k + 1) * 3 + 1] + v.z * w[(k + 2) * 3 + 1] + v.w * w[(k + 3) * 3 + 1];
        a2 += v.x * w[k * 3 + 2] + v.y * w[(k + 1) * 3 + 2] + v.z * w[(k + 2) * 3 + 2] + v.w * w[(k + 3) * 3 + 2];
    }
    out[(size_t)i * 3 + 0] = a0;
    out[(size_t)i * 3 + 1] = a1;
    out[(size_t)i * 3 + 2] = a2;
}

extern "C" void kernel_launch(void* const* d_in, const int* in_sizes, int n_in,
                              void* d_out, int out_size, void* d_ws, size_t ws_size,
                              hipStream_t stream) {
    const float* nodes = (const float*)d_in[0];
    const int* edges = (const int*)d_in[1];
    const float* ea = (const float*)d_in[2];
    const float* emb_w = (const float*)d_in[3];
    const float* emb_b = (const float*)d_in[4];
    const float* ew1 = (const float*)d_in[5];
    const float* eb1 = (const float*)d_in[6];
    const float* ew2 = (const float*)d_in[7];
    const float* eb2 = (const float*)d_in[8];
    const float* nw1 = (const float*)d_in[9];
    const float* nb1 = (const float*)d_in[10];
    const float* nw2 = (const float*)d_in[11];
    const float* nb2 = (const float*)d_in[12];
    const float* dw1 = (const float*)d_in[13];
    const float* db1 = (const float*)d_in[14];
    const float* dw2 = (const float*)d_in[15];
    const float* db2 = (const float*)d_in[16];
    const int* row = edges;
    const int* col = edges + N_EDGES;

    const size_t NH = (size_t)N_NODES * HID;
    float* r0 = (float*)d_ws;
    float* r1 = r0 + NH;
    float* r2 = r1 + NH;
    float* r3 = r2 + NH;

    float* h = r0;
    float* other = r2;

    k_embed<<<(N_NODES * HID + 255) / 256, 256, 0, stream>>>(nodes, emb_w, emb_b, h);

    const int gemm_grid = (N_NODES + 63) / 64;
    for (int l = 0; l < N_LAYERS; ++l) {
        const float* W1 = ew1 + (size_t)l * 257 * 128;
        // A = r1 = h @ W1[0:128] + b1   (no act)
        k_gemm<<<gemm_grid, 256, 0, stream>>>(h, nullptr, W1, eb1 + l * 128, r1, N_NODES, 128, 0);
        // B = other = h @ W1[128:256]   (no bias, no act)
        k_gemm<<<gemm_grid, 256, 0, stream>>>(h, nullptr, W1 + 128 * 128, nullptr, other, N_NODES, 128, 0);
        hipMemsetAsync(r3, 0, NH * sizeof(float), stream);
        k_edge<<<256, 512, 0, stream>>>(r1, other, W1 + 256 * 128, eb2 + l * 128,
                                        ew2 + (size_t)l * 128 * 128, row, col, ea, r3);
        // u = r1 = silu([h, agg] @ nw1 + nb1)
        k_gemm<<<gemm_grid, 256, 0, stream>>>(h, r3, nw1 + (size_t)l * 256 * 128, nb1 + l * 128,
                                              r1, N_NODES, 256, 1);
        // h_new = other = u @ nw2 + nb2
        k_gemm<<<gemm_grid, 256, 0, stream>>>(r1, nullptr, nw2 + (size_t)l * 128 * 128, nb2 + l * 128,
                                              other, N_NODES, 128, 0);
        float* tmp = h; h = other; other = tmp;
    }
    // decoder
    k_gemm<<<gemm_grid, 256, 0, stream>>>(h, nullptr, dw1, db1, r1, N_NODES, 128, 1);
    k_dec2<<<(N_NODES + 255) / 256, 256, 0, stream>>>(r1, dw2, db2, (float*)d_out);
}

// Round 2
// 2840.665 us; speedup vs baseline: 3.3221x; 3.3221x over previous
//
#include <hip/hip_runtime.h>

#define N_NODES 50000
#define N_EDGES 640000
#define HID 128
#define N_LAYERS 4
#define TILE_E 128

__device__ __forceinline__ float silu_f(float x) {
    return x / (1.0f + __expf(-x));
}

// h[i,c] = sum_k nodes[i,k]*emb_w[k,c] + emb_b[c]
__global__ void k_embed(const float* __restrict__ nodes, const float* __restrict__ ew,
                        const float* __restrict__ eb, float* __restrict__ h) {
    int idx = blockIdx.x * 256 + threadIdx.x;
    if (idx >= N_NODES * HID) return;
    int i = idx >> 7, c = idx & 127;
    float n0 = nodes[i * 3 + 0], n1 = nodes[i * 3 + 1], n2 = nodes[i * 3 + 2];
    h[idx] = n0 * ew[c] + n1 * ew[HID + c] + n2 * ew[2 * HID + c] + eb[c];
}

// ---- counting sort of edges by row ----
__global__ void k_hist(const int* __restrict__ row, int* __restrict__ deg) {
    int e = blockIdx.x * 256 + threadIdx.x;
    if (e < N_EDGES) atomicAdd(&deg[row[e]], 1);
}

// exclusive scan of deg[N_NODES] -> off[N_NODES]; single block of 1024
__global__ __launch_bounds__(1024) void k_scan(const int* __restrict__ deg, int* __restrict__ off) {
    __shared__ int partial[1024];
    const int t = threadIdx.x;
    const int chunk = (N_NODES + 1023) / 1024;  // 49
    const int base = t * chunk;
    int s = 0;
    for (int i = 0; i < chunk; ++i) {
        int idx = base + i;
        if (idx < N_NODES) s += deg[idx];
    }
    partial[t] = s;
    __syncthreads();
    for (int o = 1; o < 1024; o <<= 1) {
        int v = (t >= o) ? partial[t - o] : 0;
        __syncthreads();
        partial[t] += v;
        __syncthreads();
    }
    int run = (t == 0) ? 0 : partial[t - 1];
    for (int i = 0; i < chunk; ++i) {
        int idx = base + i;
        if (idx < N_NODES) {
            off[idx] = run;
            run += deg[idx];
        }
    }
}

__global__ void k_scatter(const int* __restrict__ row, const int* __restrict__ col,
                          const float* __restrict__ ea, int* __restrict__ off,
                          int* __restrict__ row_s, int* __restrict__ col_s,
                          float* __restrict__ ea_s) {
    int e = blockIdx.x * 256 + threadIdx.x;
    if (e >= N_EDGES) return;
    int r = row[e];
    int pos = atomicAdd(&off[r], 1);
    row_s[pos] = r;
    col_s[pos] = col[e];
    ea_s[pos] = ea[e];
}

// out[M,128] = act(X[M,K] @ W[K,128] + bias), X = [X1 | X2] (each row-stride 128)
__global__ __launch_bounds__(256) void k_gemm(
    const float* __restrict__ X1, const float* __restrict__ X2,
    const float* __restrict__ W, const float* __restrict__ bias,
    float* __restrict__ out, int M, int K, int do_silu) {
    __shared__ float Xs[32][68];
    __shared__ float Ws[32][128];
    const int t = threadIdx.x;
    const int m0 = blockIdx.x * 64;
    const int r0 = (t >> 5) * 8;
    const int c0 = (t & 31) * 4;
    const int lr = t >> 3;
    const int lk = (t & 7) * 4;
    float acc[8][4] = {};

    for (int kk = 0; kk < K; kk += 32) {
        const float* Xp = (X2 != nullptr && kk >= 128) ? X2 : X1;
        int kb = kk & 127;
#pragma unroll
        for (int hh = 0; hh < 2; ++hh) {
            int r = lr + hh * 32;
            int gm = m0 + r; if (gm >= M) gm = M - 1;
            float4 v = *(const float4*)&Xp[(size_t)gm * 128 + kb + lk];
            Xs[lk + 0][r] = v.x; Xs[lk + 1][r] = v.y;
            Xs[lk + 2][r] = v.z; Xs[lk + 3][r] = v.w;
        }
#pragma unroll
        for (int i = 0; i < 4; ++i) {
            int idx = t + i * 256;
            int wk = idx >> 5;
            int wc = (idx & 31) * 4;
            *(float4*)&Ws[wk][wc] = *(const float4*)&W[(size_t)(kk + wk) * 128 + wc];
        }
        __syncthreads();
#pragma unroll
        for (int k = 0; k < 32; ++k) {
            float xr[8], wr[4];
            *(float4*)&xr[0] = *(const float4*)&Xs[k][r0];
            *(float4*)&xr[4] = *(const float4*)&Xs[k][r0 + 4];
            *(float4*)&wr[0] = *(const float4*)&Ws[k][c0];
#pragma unroll
            for (int i = 0; i < 8; ++i)
#pragma unroll
                for (int j = 0; j < 4; ++j)
                    acc[i][j] += xr[i] * wr[j];
        }
        __syncthreads();
    }
    float bv[4] = {0.f, 0.f, 0.f, 0.f};
    if (bias) *(float4*)bv = *(const float4*)&bias[c0];
#pragma unroll
    for (int i = 0; i < 8; ++i) {
        int gm = m0 + r0 + i;
        if (gm < M) {
            float o[4];
#pragma unroll
            for (int j = 0; j < 4; ++j) {
                float v = acc[i][j] + bv[j];
                o[j] = do_silu ? silu_f(v) : v;
            }
            *(float4*)&out[(size_t)gm * 128 + c0] = *(float4*)o;
        }
    }
}

// Edge kernel over ROW-SORTED edges. Tile = 128 edges, 512 threads.
// m1 = silu(A[row]+B[col]+ea*w1last); m = silu(m1@W2+b2); segment-reduce per
// row run inside the tile; one atomicAdd per (segment, col) instead of per edge.
__global__ __launch_bounds__(512) void k_edge2(
    const float* __restrict__ A, const float* __restrict__ Bm,
    const float* __restrict__ w1last, const float* __restrict__ b2,
    const float* __restrict__ W2, const int* __restrict__ row_s,
    const int* __restrict__ col_s, const float* __restrict__ ea_s,
    float* __restrict__ agg) {
    __shared__ float W2s[128 * 128];
    __shared__ float m1s[TILE_E][132];
    __shared__ int rows_sh[TILE_E];
    const int t = threadIdx.x;
    for (int i = t; i < 4096; i += 512)
        ((float4*)W2s)[i] = ((const float4*)W2)[i];

    const int elA = t >> 2;          // 0..127: edge within tile (m1 phase)
    const int cA  = (t & 3) * 32;    // 32-col slab (m1 phase)
    const int p   = t >> 4;          // 0..31: edge group (GEMM: edges 4p..4p+3)
    const int c4a = (t & 15) * 4;    // cols c4a..c4a+3 and c4b..c4b+3
    const int c4b = c4a + 64;

    float w1l[32];
#pragma unroll
    for (int j = 0; j < 8; ++j)
        *(float4*)&w1l[j * 4] = *(const float4*)&w1last[cA + j * 4];
    float b2a[4], b2b[4];
    *(float4*)b2a = *(const float4*)&b2[c4a];
    *(float4*)b2b = *(const float4*)&b2[c4b];

    const int n_tiles = N_EDGES / TILE_E;  // 5000 exactly
    float av[32], bv[32], eav = 0.f;
    int r_ = 0;

    auto load_tile = [&](int tile) {
        int e = tile * TILE_E + elA;
        int r = row_s[e], c = col_s[e];
        eav = ea_s[e]; r_ = r;
        const float* Ap = A + (size_t)r * 128 + cA;
        const float* Bp = Bm + (size_t)c * 128 + cA;
#pragma unroll
        for (int j = 0; j < 8; ++j) {
            *(float4*)&av[j * 4] = *(const float4*)&Ap[j * 4];
            *(float4*)&bv[j * 4] = *(const float4*)&Bp[j * 4];
        }
    };

    int tile = blockIdx.x;
    if (tile < n_tiles) load_tile(tile);

    for (; tile < n_tiles; tile += gridDim.x) {
        __syncthreads();   // W2s ready (iter 0) / previous reduce done with m1s
        {
            float m1v[32];
#pragma unroll
            for (int j = 0; j < 32; ++j)
                m1v[j] = silu_f(av[j] + bv[j] + eav * w1l[j]);
#pragma unroll
            for (int j = 0; j < 8; ++j)
                *(float4*)&m1s[elA][cA + j * 4] = *(float4*)&m1v[j * 4];
            if ((t & 3) == 0) rows_sh[elA] = r_;
        }
        __syncthreads();   // m1 ready
        int nt = tile + gridDim.x;
        if (nt < n_tiles) load_tile(nt);   // prefetch hides under GEMM

        float acc[4][8] = {};
#pragma unroll 4
        for (int k = 0; k < 128; k += 4) {
            float4 m4[4];
#pragma unroll
            for (int e = 0; e < 4; ++e)
                m4[e] = *(const float4*)&m1s[4 * p + e][k];
#pragma unroll
            for (int kk = 0; kk < 4; ++kk) {
                float4 wa = *(const float4*)&W2s[(k + kk) * 128 + c4a];
                float4 wb = *(const float4*)&W2s[(k + kk) * 128 + c4b];
#pragma unroll
                for (int e = 0; e < 4; ++e) {
                    float mv = ((const float*)&m4[e])[kk];
                    acc[e][0] += mv * wa.x; acc[e][1] += mv * wa.y;
                    acc[e][2] += mv * wa.z; acc[e][3] += mv * wa.w;
                    acc[e][4] += mv * wb.x; acc[e][5] += mv * wb.y;
                    acc[e][6] += mv * wb.z; acc[e][7] += mv * wb.w;
                }
            }
        }
        __syncthreads();   // GEMM done reading m1s -> safe to overwrite
#pragma unroll
        for (int e = 0; e < 4; ++e) {
            float o[8];
#pragma unroll
            for (int q = 0; q < 4; ++q) o[q]     = silu_f(acc[e][q] + b2a[q]);
#pragma unroll
            for (int q = 0; q < 4; ++q) o[4 + q] = silu_f(acc[e][4 + q] + b2b[q]);
            *(float4*)&m1s[4 * p + e][c4a] = *(float4*)&o[0];
            *(float4*)&m1s[4 * p + e][c4b] = *(float4*)&o[4];
        }
        __syncthreads();   // m tile ready
        {
            const int c = t & 127, g = t >> 7;
            int e = 0, sidx = 0;
            while (e < TILE_E) {
                int r = rows_sh[e];
                int e2 = e + 1;
                while (e2 < TILE_E && rows_sh[e2] == r) ++e2;
                if ((sidx & 3) == g) {
                    float s = 0.f;
                    for (int q = e; q < e2; ++q) s += m1s[q][c];
                    atomicAdd(&agg[(size_t)r * 128 + c], s);
                }
                e = e2; ++sidx;
            }
        }
    }
}

// out[i,0..2] = u[i,:] @ dec_w2 + dec_b2
__global__ void k_dec2(const float* __restrict__ u, const float* __restrict__ w,
                       const float* __restrict__ b, float* __restrict__ out) {
    int i = blockIdx.x * 256 + threadIdx.x;
    if (i >= N_NODES) return;
    float a0 = b[0], a1 = b[1], a2 = b[2];
    const float4* u4 = (const float4*)(u + (size_t)i * 128);
#pragma unroll
    for (int k4 = 0; k4 < 32; ++k4) {
        float4 v = u4[k4];
        int k = k4 * 4;
        a0 += v.x * w[k * 3 + 0] + v.y * w[(k + 1) * 3 + 0] + v.z * w[(k + 2) * 3 + 0] + v.w * w[(k + 3) * 3 + 0];
        a1 += v.x * w[k * 3 + 1] + v.y * w[(k + 1) * 3 + 1] + v.z * w[(k + 2) * 3 + 1] + v.w * w[(k + 3) * 3 + 1];
        a2 += v.x * w[k * 3 + 2] + v.y * w[(k + 1) * 3 + 2] + v.z * w[(k + 2) * 3 + 2] + v.w * w[(k + 3) * 3 + 2];
    }
    out[(size_t)i * 3 + 0] = a0;
    out[(size_t)i * 3 + 1] = a1;
    out[(size_t)i * 3 + 2] = a2;
}

extern "C" void kernel_launch(void* const* d_in, const int* in_sizes, int n_in,
                              void* d_out, int out_size, void* d_ws, size_t ws_size,
                              hipStream_t stream) {
    const float* nodes = (const float*)d_in[0];
    const int* edges = (const int*)d_in[1];
    const float* ea = (const float*)d_in[2];
    const float* emb_w = (const float*)d_in[3];
    const float* emb_b = (const float*)d_in[4];
    const float* ew1 = (const float*)d_in[5];
    const float* eb1 = (const float*)d_in[6];
    const float* ew2 = (const float*)d_in[7];
    const float* eb2 = (const float*)d_in[8];
    const float* nw1 = (const float*)d_in[9];
    const float* nb1 = (const float*)d_in[10];
    const float* nw2 = (const float*)d_in[11];
    const float* nb2 = (const float*)d_in[12];
    const float* dw1 = (const float*)d_in[13];
    const float* db1 = (const float*)d_in[14];
    const float* dw2 = (const float*)d_in[15];
    const float* db2 = (const float*)d_in[16];
    const int* row = edges;
    const int* col = edges + N_EDGES;

    const size_t NH = (size_t)N_NODES * HID;
    float* r0 = (float*)d_ws;        // h
    float* r1 = r0 + NH;             // A / u
    float* r2 = r1 + NH;             // B / h_new
    float* r3 = r2 + NH;             // agg
    int* deg = (int*)(r3 + NH);
    int* off = deg + N_NODES;
    int* row_s = off + N_NODES;
    int* col_s = row_s + N_EDGES;
    float* ea_s = (float*)(col_s + N_EDGES);

    float* h = r0;
    float* other = r2;

    // --- one-time per launch: counting sort of edges by row ---
    hipMemsetAsync(deg, 0, N_NODES * sizeof(int), stream);
    k_hist<<<(N_EDGES + 255) / 256, 256, 0, stream>>>(row, deg);
    k_scan<<<1, 1024, 0, stream>>>(deg, off);
    k_scatter<<<(N_EDGES + 255) / 256, 256, 0, stream>>>(row, col, ea, off, row_s, col_s, ea_s);

    k_embed<<<(N_NODES * HID + 255) / 256, 256, 0, stream>>>(nodes, emb_w, emb_b, h);

    const int gemm_grid = (N_NODES + 63) / 64;
    for (int l = 0; l < N_LAYERS; ++l) {
        const float* W1 = ew1 + (size_t)l * 257 * 128;
        k_gemm<<<gemm_grid, 256, 0, stream>>>(h, nullptr, W1, eb1 + l * 128, r1, N_NODES, 128, 0);
        k_gemm<<<gemm_grid, 256, 0, stream>>>(h, nullptr, W1 + 128 * 128, nullptr, other, N_NODES, 128, 0);
        hipMemsetAsync(r3, 0, NH * sizeof(float), stream);
        k_edge2<<<256, 512, 0, stream>>>(r1, other, W1 + 256 * 128, eb2 + l * 128,
                                         ew2 + (size_t)l * 128 * 128, row_s, col_s, ea_s, r3);
        k_gemm<<<gemm_grid, 256, 0, stream>>>(h, r3, nw1 + (size_t)l * 256 * 128, nb1 + l * 128,
                                              r1, N_NODES, 256, 1);
        k_gemm<<<gemm_grid, 256, 0, stream>>>(r1, nullptr, nw2 + (size_t)l * 128 * 128, nb2 + l * 128,
                                              other, N_NODES, 128, 0);
        float* tmp = h; h = other; other = tmp;
    }
    k_gemm<<<gemm_grid, 256, 0, stream>>>(h, nullptr, dw1, db1, r1, N_NODES, 128, 1);
    k_dec2<<<(N_NODES + 255) / 256, 256, 0, stream>>>(r1, dw2, db2, (float*)d_out);
}

// Round 3
// 1640.729 us; speedup vs baseline: 5.7517x; 1.7313x over previous
//
#include <hip/hip_runtime.h>

#define N_NODES 50000
#define N_EDGES 640000
#define HID 128
#define N_LAYERS 4
#define TILE_E 128

typedef _Float16 f16x8 __attribute__((ext_vector_type(8)));
typedef float f32x16 __attribute__((ext_vector_type(16)));

__device__ __forceinline__ float silu_f(float x) {
    return x / (1.0f + __expf(-x));
}

__device__ __forceinline__ f32x16 zero16() {
    f32x16 z;
#pragma unroll
    for (int i = 0; i < 16; ++i) z[i] = 0.f;
    return z;
}

// h[i,c] = sum_k nodes[i,k]*emb_w[k,c] + emb_b[c]
__global__ void k_embed(const float* __restrict__ nodes, const float* __restrict__ ew,
                        const float* __restrict__ eb, float* __restrict__ h) {
    int idx = blockIdx.x * 256 + threadIdx.x;
    if (idx >= N_NODES * HID) return;
    int i = idx >> 7, c = idx & 127;
    float n0 = nodes[i * 3 + 0], n1 = nodes[i * 3 + 1], n2 = nodes[i * 3 + 2];
    h[idx] = n0 * ew[c] + n1 * ew[HID + c] + n2 * ew[2 * HID + c] + eb[c];
}

// ---- counting sort of edges by row ----
__global__ void k_hist(const int* __restrict__ row, int* __restrict__ deg) {
    int e = blockIdx.x * 256 + threadIdx.x;
    if (e < N_EDGES) atomicAdd(&deg[row[e]], 1);
}

__global__ __launch_bounds__(1024) void k_scan(const int* __restrict__ deg, int* __restrict__ off) {
    __shared__ int partial[1024];
    const int t = threadIdx.x;
    const int chunk = (N_NODES + 1023) / 1024;
    const int base = t * chunk;
    int s = 0;
    for (int i = 0; i < chunk; ++i) {
        int idx = base + i;
        if (idx < N_NODES) s += deg[idx];
    }
    partial[t] = s;
    __syncthreads();
    for (int o = 1; o < 1024; o <<= 1) {
        int v = (t >= o) ? partial[t - o] : 0;
        __syncthreads();
        partial[t] += v;
        __syncthreads();
    }
    int run = (t == 0) ? 0 : partial[t - 1];
    for (int i = 0; i < chunk; ++i) {
        int idx = base + i;
        if (idx < N_NODES) {
            off[idx] = run;
            run += deg[idx];
        }
    }
}

__global__ void k_scatter(const int* __restrict__ row, const int* __restrict__ col,
                          const float* __restrict__ ea, int* __restrict__ off,
                          int* __restrict__ row_s, int* __restrict__ col_s,
                          float* __restrict__ ea_s) {
    int e = blockIdx.x * 256 + threadIdx.x;
    if (e >= N_EDGES) return;
    int r = row[e];
    int pos = atomicAdd(&off[r], 1);
    row_s[pos] = r;
    col_s[pos] = col[e];
    ea_s[pos] = ea[e];
}

// Pack W2[l] (128x128 f32, row-major k x col) into MFMA B-fragment order, f16.
// frag block blk = cb*8+kb (1KB): lane l holds col=cb*32+(l&31), k=kb*16+(l>>5)*8+j
__global__ __launch_bounds__(256) void k_packW2(const float* __restrict__ W2all,
                                                _Float16* __restrict__ W2p) {
    const int layer = blockIdx.x;
    const float* W2 = W2all + (size_t)layer * 128 * 128;
    _Float16* out = W2p + (size_t)layer * 128 * 128;
    const int t = threadIdx.x;
    for (int fl = t; fl < 2048; fl += 256) {
        int blk = fl >> 6, lane = fl & 63;
        int cb = blk >> 3, kb = blk & 7;
        int colg = cb * 32 + (lane & 31);
        int kbase = kb * 16 + (lane >> 5) * 8;
        f16x8 v;
#pragma unroll
        for (int j = 0; j < 8; ++j)
            v[j] = (_Float16)W2[(size_t)(kbase + j) * 128 + colg];
        *(f16x8*)&out[(size_t)fl * 8] = v;
    }
}

// fp32 GEMM for node MLPs: out[M,128] = act(X[M,K]@W[K,128]+bias), X=[X1|X2]
__global__ __launch_bounds__(256) void k_gemm(
    const float* __restrict__ X1, const float* __restrict__ X2,
    const float* __restrict__ W, const float* __restrict__ bias,
    float* __restrict__ out, int M, int K, int do_silu) {
    __shared__ float Xs[32][68];
    __shared__ float Ws[32][128];
    const int t = threadIdx.x;
    const int m0 = blockIdx.x * 64;
    const int r0 = (t >> 5) * 8;
    const int c0 = (t & 31) * 4;
    const int lr = t >> 3;
    const int lk = (t & 7) * 4;
    float acc[8][4] = {};

    for (int kk = 0; kk < K; kk += 32) {
        const float* Xp = (X2 != nullptr && kk >= 128) ? X2 : X1;
        int kb = kk & 127;
#pragma unroll
        for (int hh = 0; hh < 2; ++hh) {
            int r = lr + hh * 32;
            int gm = m0 + r; if (gm >= M) gm = M - 1;
            float4 v = *(const float4*)&Xp[(size_t)gm * 128 + kb + lk];
            Xs[lk + 0][r] = v.x; Xs[lk + 1][r] = v.y;
            Xs[lk + 2][r] = v.z; Xs[lk + 3][r] = v.w;
        }
#pragma unroll
        for (int i = 0; i < 4; ++i) {
            int idx = t + i * 256;
            int wk = idx >> 5;
            int wc = (idx & 31) * 4;
            *(float4*)&Ws[wk][wc] = *(const float4*)&W[(size_t)(kk + wk) * 128 + wc];
        }
        __syncthreads();
#pragma unroll
        for (int k = 0; k < 32; ++k) {
            float xr[8], wr[4];
            *(float4*)&xr[0] = *(const float4*)&Xs[k][r0];
            *(float4*)&xr[4] = *(const float4*)&Xs[k][r0 + 4];
            *(float4*)&wr[0] = *(const float4*)&Ws[k][c0];
#pragma unroll
            for (int i = 0; i < 8; ++i)
#pragma unroll
                for (int j = 0; j < 4; ++j)
                    acc[i][j] += xr[i] * wr[j];
        }
        __syncthreads();
    }
    float bv[4] = {0.f, 0.f, 0.f, 0.f};
    if (bias) *(float4*)bv = *(const float4*)&bias[c0];
#pragma unroll
    for (int i = 0; i < 8; ++i) {
        int gm = m0 + r0 + i;
        if (gm < M) {
            float o[4];
#pragma unroll
            for (int j = 0; j < 4; ++j) {
                float v = acc[i][j] + bv[j];
                o[j] = do_silu ? silu_f(v) : v;
            }
            *(float4*)&out[(size_t)gm * 128 + c0] = *(float4*)o;
        }
    }
}

// Edge kernel, MFMA version. Row-sorted edges, tile=128, 512 threads (8 waves).
// m1 = silu(A[row]+B[col]+ea*w1l) computed fp32, stored f16 in A-frag layout;
// GEMM via mfma_f32_32x32x16_f16 against prepacked W2; silu epilogue; in-tile
// segment reduce; one atomicAdd per (segment, col).
__global__ __launch_bounds__(512, 4) void k_edge3(
    const float* __restrict__ A, const float* __restrict__ Bm,
    const float* __restrict__ w1last, const float* __restrict__ b2,
    const _Float16* __restrict__ W2p, const int* __restrict__ row_s,
    const int* __restrict__ col_s, const float* __restrict__ ea_s,
    float* __restrict__ agg) {
    __shared__ __align__(16) _Float16 W2s[16384];
    __shared__ __align__(16) _Float16 m1f[16384];   // A-frags, then reused as mo[128][128]
    __shared__ int rows_sh[TILE_E];
    const int t = threadIdx.x;

    // stage packed W2 (32KB) once
    for (int i = t; i < 2048; i += 512)
        ((float4*)W2s)[i] = ((const float4*)W2p)[i];

    // m1-phase mapping
    const int e = t >> 2;            // edge in tile 0..127
    const int slab = (t & 3) * 32;   // k-cols slab
    const int rb_e = e >> 5;
    const int e31 = e & 31;
    // GEMM-phase mapping
    const int w = t >> 6;            // wave 0..7
    const int l = t & 63;
    const int rb = w & 3;            // row block (32 edges)
    const int cbp = w >> 2;          // 0..1 -> col blocks 2cbp, 2cbp+1
    const int cb0 = cbp * 2, cb1 = cb0 + 1;
    const int colL = l & 31;
    const int hi = l >> 5;
    const float b20 = b2[cb0 * 32 + colL];
    const float b21 = b2[cb1 * 32 + colL];

    const f16x8* m1v = (const f16x8*)m1f;
    const f16x8* w2v = (const f16x8*)W2s;
    _Float16* mo = m1f;

    const int n_tiles = N_EDGES / TILE_E;  // 5000

    for (int tile = blockIdx.x; tile < n_tiles; tile += gridDim.x) {
        __syncthreads();   // prev reduce done; m1f/rows_sh free; W2s staged (iter0)

        // ---- phase 1: gather + m1 + store f16 A-frags ----
        {
            int eg = tile * TILE_E + e;
            int r = row_s[eg], c = col_s[eg];
            float eav = ea_s[eg];
            const float4* Ap4 = (const float4*)(A + (size_t)r * 128);
            const float4* Bp4 = (const float4*)(Bm + (size_t)c * 128);
            const float4* Wp4 = (const float4*)w1last;
#pragma unroll
            for (int half = 0; half < 2; ++half) {
                int k0 = slab + 16 * half;
                int kb = k0 >> 4;
                float4 a4[4], b4[4], w4[4];
#pragma unroll
                for (int j = 0; j < 4; ++j) {
                    a4[j] = Ap4[(k0 >> 2) + j];
                    b4[j] = Bp4[(k0 >> 2) + j];
                    w4[j] = Wp4[(k0 >> 2) + j];
                }
                float m[16];
#pragma unroll
                for (int j = 0; j < 4; ++j) {
                    const float* af = (const float*)&a4[j];
                    const float* bf = (const float*)&b4[j];
                    const float* wf = (const float*)&w4[j];
#pragma unroll
                    for (int q = 0; q < 4; ++q)
                        m[j * 4 + q] = silu_f(af[q] + bf[q] + eav * wf[q]);
                }
                f16x8 lo8, hi8;
#pragma unroll
                for (int j = 0; j < 8; ++j) { lo8[j] = (_Float16)m[j]; hi8[j] = (_Float16)m[8 + j]; }
                int base = (rb_e * 8 + kb) * 512;   // frag block base (elements)
                *(f16x8*)&m1f[base + e31 * 8] = lo8;
                *(f16x8*)&m1f[base + (e31 + 32) * 8] = hi8;
            }
            if ((t & 3) == 0) rows_sh[e] = r;
        }
        __syncthreads();   // m1 frags ready

        // ---- phase 2: MFMA GEMM ----
        f32x16 acc0 = zero16(), acc1 = zero16();
#pragma unroll
        for (int kb = 0; kb < 8; ++kb) {
            f16x8 a = m1v[(rb * 8 + kb) * 64 + l];
            acc0 = __builtin_amdgcn_mfma_f32_32x32x16_f16(a, w2v[(cb0 * 8 + kb) * 64 + l], acc0, 0, 0, 0);
            acc1 = __builtin_amdgcn_mfma_f32_32x32x16_f16(a, w2v[(cb1 * 8 + kb) * 64 + l], acc1, 0, 0, 0);
        }
        __syncthreads();   // all waves done reading m1 frags

        // ---- phase 3: epilogue silu -> mo (f16 row-major [128][128]) ----
#pragma unroll
        for (int r = 0; r < 16; ++r) {
            int rowi = (r & 3) + 8 * (r >> 2) + 4 * hi;
            int erow = rb * 32 + rowi;
            mo[erow * 128 + cb0 * 32 + colL] = (_Float16)silu_f(acc0[r] + b20);
            mo[erow * 128 + cb1 * 32 + colL] = (_Float16)silu_f(acc1[r] + b21);
        }
        __syncthreads();   // mo ready

        // ---- phase 4: segment reduce + atomics ----
        {
            const int c = t & 127, g = t >> 7;
            int ei = 0, sidx = 0;
            while (ei < TILE_E) {
                int r = rows_sh[ei];
                int e2 = ei + 1;
                while (e2 < TILE_E && rows_sh[e2] == r) ++e2;
                if ((sidx & 3) == g) {
                    float s = 0.f;
                    for (int q = ei; q < e2; ++q) s += (float)mo[q * 128 + c];
                    atomicAdd(&agg[(size_t)r * 128 + c], s);
                }
                ei = e2; ++sidx;
            }
        }
    }
}

// out[i,0..2] = u[i,:] @ dec_w2 + dec_b2
__global__ void k_dec2(const float* __restrict__ u, const float* __restrict__ w,
                       const float* __restrict__ b, float* __restrict__ out) {
    int i = blockIdx.x * 256 + threadIdx.x;
    if (i >= N_NODES) return;
    float a0 = b[0], a1 = b[1], a2 = b[2];
    const float4* u4 = (const float4*)(u + (size_t)i * 128);
#pragma unroll
    for (int k4 = 0; k4 < 32; ++k4) {
        float4 v = u4[k4];
        int k = k4 * 4;
        a0 += v.x * w[k * 3 + 0] + v.y * w[(k + 1) * 3 + 0] + v.z * w[(k + 2) * 3 + 0] + v.w * w[(k + 3) * 3 + 0];
        a1 += v.x * w[k * 3 + 1] + v.y * w[(k + 1) * 3 + 1] + v.z * w[(k + 2) * 3 + 1] + v.w * w[(k + 3) * 3 + 1];
        a2 += v.x * w[k * 3 + 2] + v.y * w[(k + 1) * 3 + 2] + v.z * w[(k + 2) * 3 + 2] + v.w * w[(k + 3) * 3 + 2];
    }
    out[(size_t)i * 3 + 0] = a0;
    out[(size_t)i * 3 + 1] = a1;
    out[(size_t)i * 3 + 2] = a2;
}

extern "C" void kernel_launch(void* const* d_in, const int* in_sizes, int n_in,
                              void* d_out, int out_size, void* d_ws, size_t ws_size,
                              hipStream_t stream) {
    const float* nodes = (const float*)d_in[0];
    const int* edges = (const int*)d_in[1];
    const float* ea = (const float*)d_in[2];
    const float* emb_w = (const float*)d_in[3];
    const float* emb_b = (const float*)d_in[4];
    const float* ew1 = (const float*)d_in[5];
    const float* eb1 = (const float*)d_in[6];
    const float* ew2 = (const float*)d_in[7];
    const float* eb2 = (const float*)d_in[8];
    const float* nw1 = (const float*)d_in[9];
    const float* nb1 = (const float*)d_in[10];
    const float* nw2 = (const float*)d_in[11];
    const float* nb2 = (const float*)d_in[12];
    const float* dw1 = (const float*)d_in[13];
    const float* db1 = (const float*)d_in[14];
    const float* dw2 = (const float*)d_in[15];
    const float* db2 = (const float*)d_in[16];
    const int* row = edges;
    const int* col = edges + N_EDGES;

    const size_t NH = (size_t)N_NODES * HID;
    float* r0 = (float*)d_ws;        // h
    float* r1 = r0 + NH;             // A / u
    float* r2 = r1 + NH;             // B / h_new
    float* r3 = r2 + NH;             // agg
    int* deg = (int*)(r3 + NH);
    int* off = deg + N_NODES;
    int* row_s = off + N_NODES;
    int* col_s = row_s + N_EDGES;
    float* ea_s = (float*)(col_s + N_EDGES);
    _Float16* W2p = (_Float16*)(ea_s + N_EDGES);  // 4 x 128 x 128 f16 (16B-aligned)

    float* h = r0;
    float* other = r2;

    // one-time: counting sort of edges by row + W2 fragment pre-pack
    hipMemsetAsync(deg, 0, N_NODES * sizeof(int), stream);
    k_hist<<<(N_EDGES + 255) / 256, 256, 0, stream>>>(row, deg);
    k_scan<<<1, 1024, 0, stream>>>(deg, off);
    k_scatter<<<(N_EDGES + 255) / 256, 256, 0, stream>>>(row, col, ea, off, row_s, col_s, ea_s);
    k_packW2<<<N_LAYERS, 256, 0, stream>>>(ew2, W2p);

    k_embed<<<(N_NODES * HID + 255) / 256, 256, 0, stream>>>(nodes, emb_w, emb_b, h);

    const int gemm_grid = (N_NODES + 63) / 64;
    for (int l = 0; l < N_LAYERS; ++l) {
        const float* W1 = ew1 + (size_t)l * 257 * 128;
        k_gemm<<<gemm_grid, 256, 0, stream>>>(h, nullptr, W1, eb1 + l * 128, r1, N_NODES, 128, 0);
        k_gemm<<<gemm_grid, 256, 0, stream>>>(h, nullptr, W1 + 128 * 128, nullptr, other, N_NODES, 128, 0);
        hipMemsetAsync(r3, 0, NH * sizeof(float), stream);
        k_edge3<<<512, 512, 0, stream>>>(r1, other, W1 + 256 * 128, eb2 + l * 128,
                                         W2p + (size_t)l * 128 * 128, row_s, col_s, ea_s, r3);
        k_gemm<<<gemm_grid, 256, 0, stream>>>(h, r3, nw1 + (size_t)l * 256 * 128, nb1 + l * 128,
                                              r1, N_NODES, 256, 1);
        k_gemm<<<gemm_grid, 256, 0, stream>>>(r1, nullptr, nw2 + (size_t)l * 128 * 128, nb2 + l * 128,
                                              other, N_NODES, 128, 0);
        float* tmp = h; h = other; other = tmp;
    }
    k_gemm<<<gemm_grid, 256, 0, stream>>>(h, nullptr, dw1, db1, r1, N_NODES, 128, 1);
    k_dec2<<<(N_NODES + 255) / 256, 256, 0, stream>>>(r1, dw2, db2, (float*)d_out);
}

// Round 4
// 1224.497 us; speedup vs baseline: 7.7069x; 1.3399x over previous
//
#include <hip/hip_runtime.h>

#define N_NODES 50000
#define N_EDGES 640000
#define HID 128
#define N_LAYERS 4
#define TILE_E 128

typedef _Float16 f16x8 __attribute__((ext_vector_type(8)));
typedef float f32x16 __attribute__((ext_vector_type(16)));

__device__ __forceinline__ float silu_f(float x) {
    return x * __builtin_amdgcn_rcpf(1.0f + __expf(-x));
}

__device__ __forceinline__ f32x16 zero16() {
    f32x16 z;
#pragma unroll
    for (int i = 0; i < 16; ++i) z[i] = 0.f;
    return z;
}

// h[i,c] = sum_k nodes[i,k]*emb_w[k,c] + emb_b[c]
__global__ void k_embed(const float* __restrict__ nodes, const float* __restrict__ ew,
                        const float* __restrict__ eb, float* __restrict__ h) {
    int idx = blockIdx.x * 256 + threadIdx.x;
    if (idx >= N_NODES * HID) return;
    int i = idx >> 7, c = idx & 127;
    float n0 = nodes[i * 3 + 0], n1 = nodes[i * 3 + 1], n2 = nodes[i * 3 + 2];
    h[idx] = n0 * ew[c] + n1 * ew[HID + c] + n2 * ew[2 * HID + c] + eb[c];
}

// ---- counting sort of edges by row ----
__global__ void k_hist(const int* __restrict__ row, int* __restrict__ deg) {
    int e = blockIdx.x * 256 + threadIdx.x;
    if (e < N_EDGES) atomicAdd(&deg[row[e]], 1);
}

__global__ __launch_bounds__(1024) void k_scan(const int* __restrict__ deg, int* __restrict__ off) {
    __shared__ int partial[1024];
    const int t = threadIdx.x;
    const int chunk = (N_NODES + 1023) / 1024;
    const int base = t * chunk;
    int s = 0;
    for (int i = 0; i < chunk; ++i) {
        int idx = base + i;
        if (idx < N_NODES) s += deg[idx];
    }
    partial[t] = s;
    __syncthreads();
    for (int o = 1; o < 1024; o <<= 1) {
        int v = (t >= o) ? partial[t - o] : 0;
        __syncthreads();
        partial[t] += v;
        __syncthreads();
    }
    int run = (t == 0) ? 0 : partial[t - 1];
    for (int i = 0; i < chunk; ++i) {
        int idx = base + i;
        if (idx < N_NODES) {
            off[idx] = run;
            run += deg[idx];
        }
    }
}

__global__ void k_scatter(const int* __restrict__ row, const int* __restrict__ col,
                          const float* __restrict__ ea, int* __restrict__ off,
                          int* __restrict__ row_s, int* __restrict__ col_s,
                          float* __restrict__ ea_s) {
    int e = blockIdx.x * 256 + threadIdx.x;
    if (e >= N_EDGES) return;
    int r = row[e];
    int pos = atomicAdd(&off[r], 1);
    row_s[pos] = r;
    col_s[pos] = col[e];
    ea_s[pos] = ea[e];
}

// Pack W2[l] (128x128 f32, row-major k x col) into MFMA B-fragment order, f16.
// frag block blk = cb*8+kb: lane l holds col=cb*32+(l&31), k=kb*16+(l>>5)*8+j
__global__ __launch_bounds__(256) void k_packW2(const float* __restrict__ W2all,
                                                _Float16* __restrict__ W2p) {
    const int layer = blockIdx.x;
    const float* W2 = W2all + (size_t)layer * 128 * 128;
    _Float16* out = W2p + (size_t)layer * 128 * 128;
    const int t = threadIdx.x;
    for (int fl = t; fl < 2048; fl += 256) {
        int blk = fl >> 6, lane = fl & 63;
        int cb = blk >> 3, kb = blk & 7;
        int colg = cb * 32 + (lane & 31);
        int kbase = kb * 16 + (lane >> 5) * 8;
        f16x8 v;
#pragma unroll
        for (int j = 0; j < 8; ++j)
            v[j] = (_Float16)W2[(size_t)(kbase + j) * 128 + colg];
        *(f16x8*)&out[(size_t)fl * 8] = v;
    }
}

// fp32 GEMM for node MLPs: out[M,128] = act(X[M,K]@W[K,128]+bias), X=[X1|X2]
__global__ __launch_bounds__(256) void k_gemm(
    const float* __restrict__ X1, const float* __restrict__ X2,
    const float* __restrict__ W, const float* __restrict__ bias,
    float* __restrict__ out, int M, int K, int do_silu) {
    __shared__ float Xs[32][68];
    __shared__ float Ws[32][128];
    const int t = threadIdx.x;
    const int m0 = blockIdx.x * 64;
    const int r0 = (t >> 5) * 8;
    const int c0 = (t & 31) * 4;
    const int lr = t >> 3;
    const int lk = (t & 7) * 4;
    float acc[8][4] = {};

    for (int kk = 0; kk < K; kk += 32) {
        const float* Xp = (X2 != nullptr && kk >= 128) ? X2 : X1;
        int kb = kk & 127;
#pragma unroll
        for (int hh = 0; hh < 2; ++hh) {
            int r = lr + hh * 32;
            int gm = m0 + r; if (gm >= M) gm = M - 1;
            float4 v = *(const float4*)&Xp[(size_t)gm * 128 + kb + lk];
            Xs[lk + 0][r] = v.x; Xs[lk + 1][r] = v.y;
            Xs[lk + 2][r] = v.z; Xs[lk + 3][r] = v.w;
        }
#pragma unroll
        for (int i = 0; i < 4; ++i) {
            int idx = t + i * 256;
            int wk = idx >> 5;
            int wc = (idx & 31) * 4;
            *(float4*)&Ws[wk][wc] = *(const float4*)&W[(size_t)(kk + wk) * 128 + wc];
        }
        __syncthreads();
#pragma unroll
        for (int k = 0; k < 32; ++k) {
            float xr[8], wr[4];
            *(float4*)&xr[0] = *(const float4*)&Xs[k][r0];
            *(float4*)&xr[4] = *(const float4*)&Xs[k][r0 + 4];
            *(float4*)&wr[0] = *(const float4*)&Ws[k][c0];
#pragma unroll
            for (int i = 0; i < 8; ++i)
#pragma unroll
                for (int j = 0; j < 4; ++j)
                    acc[i][j] += xr[i] * wr[j];
        }
        __syncthreads();
    }
    float bv[4] = {0.f, 0.f, 0.f, 0.f};
    if (bias) *(float4*)bv = *(const float4*)&bias[c0];
#pragma unroll
    for (int i = 0; i < 8; ++i) {
        int gm = m0 + r0 + i;
        if (gm < M) {
            float o[4];
#pragma unroll
            for (int j = 0; j < 4; ++j) {
                float v = acc[i][j] + bv[j];
                o[j] = do_silu ? silu_f(v) : v;
            }
            *(float4*)&out[(size_t)gm * 128 + c0] = *(float4*)o;
        }
    }
}

// Edge kernel v4. Row-sorted edges, tile=128, 512 threads (8 waves).
// Conflict-free frag writes, ballot-based segment list, rcp-silu, B prefetch.
__global__ __launch_bounds__(512, 4) void k_edge4(
    const float* __restrict__ A, const float* __restrict__ Bm,
    const float* __restrict__ w1last, const float* __restrict__ b2,
    const _Float16* __restrict__ W2p, const int* __restrict__ row_s,
    const int* __restrict__ col_s, const float* __restrict__ ea_s,
    float* __restrict__ agg) {
    __shared__ __align__(16) _Float16 W2s[16384];
    __shared__ __align__(16) _Float16 m1f[TILE_E * 136];  // frags, then mo[128][136]
    __shared__ int rows_sh[TILE_E];
    __shared__ int segs_sh[TILE_E + 2];
    __shared__ unsigned long long masks_sh[2];

    const int t = threadIdx.x;
    const int w = t >> 6, l = t & 63;
    const int lane31 = l & 31, hi = l >> 5;

    for (int i = t; i < 2048; i += 512)
        ((float4*)W2s)[i] = ((const float4*)W2p)[i];

    // phase-1 mapping: this thread computes edge e_mine, k chunks kbase0 + j*16 + [0,8)
    const int e_mine = (w >> 1) * 32 + lane31;
    const int kbase0 = (w & 1) * 64 + hi * 8;

    // GEMM / epilogue mapping
    const int rb_g = w & 3;
    const int cb0 = (w >> 2) * 2, cb1 = cb0 + 1;
    const float b20 = b2[cb0 * 32 + lane31];
    const float b21 = b2[cb1 * 32 + lane31];

    const f16x8* m1v = (const f16x8*)m1f;
    const f16x8* w2v = (const f16x8*)W2s;
    _Float16* mo = m1f;

    const int n_tiles = N_EDGES / TILE_E;  // 5000
    const int stride = gridDim.x;

    int r_pf = 0; float ea_pf = 0.f;
    float bpf[32];

    auto issue_pf = [&](int tile) {
        int eg = tile * TILE_E + e_mine;
        r_pf = row_s[eg];
        int c = col_s[eg];
        ea_pf = ea_s[eg];
        const float* Bp = Bm + (size_t)c * 128;
#pragma unroll
        for (int j = 0; j < 4; ++j) {
            int k0 = kbase0 + j * 16;
            *(float4*)&bpf[j * 8] = *(const float4*)&Bp[k0];
            *(float4*)&bpf[j * 8 + 4] = *(const float4*)&Bp[k0 + 4];
        }
    };

    int tile = blockIdx.x;
    if (tile < n_tiles) issue_pf(tile);

    for (; tile < n_tiles; tile += stride) {
        __syncthreads();  // prev phase4 done with mo; W2s staged (iter 0)

        // ---- phase 1: m1 = silu(A[row]+B[col]+ea*w1l) -> f16 A-frags ----
        {
            const int r = r_pf;
            const float eav = ea_pf;
            const float* Ap = A + (size_t)r * 128;
#pragma unroll
            for (int j = 0; j < 4; ++j) {
                int k0 = kbase0 + j * 16;
                float av[8], wv_[8];
                *(float4*)&av[0] = *(const float4*)&Ap[k0];
                *(float4*)&av[4] = *(const float4*)&Ap[k0 + 4];
                *(float4*)&wv_[0] = *(const float4*)&w1last[k0];
                *(float4*)&wv_[4] = *(const float4*)&w1last[k0 + 4];
                f16x8 o;
#pragma unroll
                for (int q = 0; q < 8; ++q)
                    o[q] = (_Float16)silu_f(av[q] + bpf[j * 8 + q] + eav * wv_[q]);
                *(f16x8*)&m1f[(w * 4 + j) * 512 + l * 8] = o;  // contiguous 1KB/wave/j
            }
            if ((w & 1) == 0 && hi == 0) rows_sh[e_mine] = r;
        }
        __syncthreads();  // frags + rows_sh ready

        // ballot segment-start masks (waves 0,1 only; wave-uniform branch)
        if (t < 128) {
            bool flag = (t == 0) || (rows_sh[t] != rows_sh[t - 1]);
            unsigned long long m = __ballot(flag);
            if ((t & 63) == 0) masks_sh[t >> 6] = m;
        }

        // prefetch next tile's B + indices (latency hides under MFMA/epilogue)
        int nt = tile + stride;
        if (nt < n_tiles) issue_pf(nt);

        // ---- phase 2: MFMA ----
        f32x16 acc0 = zero16(), acc1 = zero16();
#pragma unroll
        for (int kb = 0; kb < 8; ++kb) {
            f16x8 a = m1v[(rb_g * 8 + kb) * 64 + l];
            acc0 = __builtin_amdgcn_mfma_f32_32x32x16_f16(a, w2v[(cb0 * 8 + kb) * 64 + l], acc0, 0, 0, 0);
            acc1 = __builtin_amdgcn_mfma_f32_32x32x16_f16(a, w2v[(cb1 * 8 + kb) * 64 + l], acc1, 0, 0, 0);
        }
        __syncthreads();  // frags consumed; masks visible

        // segment list from masks (popcount-prefix; O(1) per thread)
        const unsigned long long m0 = masks_sh[0], m1m = masks_sh[1];
        const int ns = __popcll(m0) + __popcll(m1m);
        if (t < 128) {
            bool bit = (t < 64) ? ((m0 >> t) & 1ull) : ((m1m >> (t - 64)) & 1ull);
            if (bit) {
                int idx = (t < 64) ? __popcll(m0 & ((1ull << t) - 1))
                                   : __popcll(m0) + __popcll(m1m & ((1ull << (t - 64)) - 1));
                segs_sh[idx] = t;
            }
        }
        if (t == 0) segs_sh[ns] = TILE_E;

        // ---- phase 3: silu epilogue -> mo[128][136] f16 ----
#pragma unroll
        for (int r = 0; r < 16; ++r) {
            int rowi = (r & 3) + 8 * (r >> 2) + 4 * hi;
            int erow = rb_g * 32 + rowi;
            mo[erow * 136 + cb0 * 32 + lane31] = (_Float16)silu_f(acc0[r] + b20);
            mo[erow * 136 + cb1 * 32 + lane31] = (_Float16)silu_f(acc1[r] + b21);
        }
        __syncthreads();  // mo + segs ready

        // ---- phase 4: per-segment column sums + one atomic per (segment,col) ----
        {
            const int c = t & 127, g = t >> 7;
            for (int s = g; s < ns; s += 4) {
                int st = segs_sh[s], en = segs_sh[s + 1];
                float sum = 0.f;
                for (int q = st; q < en; ++q) sum += (float)mo[q * 136 + c];
                atomicAdd(&agg[(size_t)rows_sh[st] * 128 + c], sum);
            }
        }
    }
}

// out[i,0..2] = u[i,:] @ dec_w2 + dec_b2
__global__ void k_dec2(const float* __restrict__ u, const float* __restrict__ w,
                       const float* __restrict__ b, float* __restrict__ out) {
    int i = blockIdx.x * 256 + threadIdx.x;
    if (i >= N_NODES) return;
    float a0 = b[0], a1 = b[1], a2 = b[2];
    const float4* u4 = (const float4*)(u + (size_t)i * 128);
#pragma unroll
    for (int k4 = 0; k4 < 32; ++k4) {
        float4 v = u4[k4];
        int k = k4 * 4;
        a0 += v.x * w[k * 3 + 0] + v.y * w[(k + 1) * 3 + 0] + v.z * w[(k + 2) * 3 + 0] + v.w * w[(k + 3) * 3 + 0];
        a1 += v.x * w[k * 3 + 1] + v.y * w[(k + 1) * 3 + 1] + v.z * w[(k + 2) * 3 + 1] + v.w * w[(k + 3) * 3 + 1];
        a2 += v.x * w[k * 3 + 2] + v.y * w[(k + 1) * 3 + 2] + v.z * w[(k + 2) * 3 + 2] + v.w * w[(k + 3) * 3 + 2];
    }
    out[(size_t)i * 3 + 0] = a0;
    out[(size_t)i * 3 + 1] = a1;
    out[(size_t)i * 3 + 2] = a2;
}

extern "C" void kernel_launch(void* const* d_in, const int* in_sizes, int n_in,
                              void* d_out, int out_size, void* d_ws, size_t ws_size,
                              hipStream_t stream) {
    const float* nodes = (const float*)d_in[0];
    const int* edges = (const int*)d_in[1];
    const float* ea = (const float*)d_in[2];
    const float* emb_w = (const float*)d_in[3];
    const float* emb_b = (const float*)d_in[4];
    const float* ew1 = (const float*)d_in[5];
    const float* eb1 = (const float*)d_in[6];
    const float* ew2 = (const float*)d_in[7];
    const float* eb2 = (const float*)d_in[8];
    const float* nw1 = (const float*)d_in[9];
    const float* nb1 = (const float*)d_in[10];
    const float* nw2 = (const float*)d_in[11];
    const float* nb2 = (const float*)d_in[12];
    const float* dw1 = (const float*)d_in[13];
    const float* db1 = (const float*)d_in[14];
    const float* dw2 = (const float*)d_in[15];
    const float* db2 = (const float*)d_in[16];
    const int* row = edges;
    const int* col = edges + N_EDGES;

    const size_t NH = (size_t)N_NODES * HID;
    float* r0 = (float*)d_ws;        // h
    float* r1 = r0 + NH;             // A / u
    float* r2 = r1 + NH;             // B / h_new
    float* r3 = r2 + NH;             // agg
    int* deg = (int*)(r3 + NH);
    int* off = deg + N_NODES;
    int* row_s = off + N_NODES;
    int* col_s = row_s + N_EDGES;
    float* ea_s = (float*)(col_s + N_EDGES);
    _Float16* W2p = (_Float16*)(ea_s + N_EDGES);

    float* h = r0;
    float* other = r2;

    // one-time: counting sort by row + W2 fragment pre-pack
    hipMemsetAsync(deg, 0, N_NODES * sizeof(int), stream);
    k_hist<<<(N_EDGES + 255) / 256, 256, 0, stream>>>(row, deg);
    k_scan<<<1, 1024, 0, stream>>>(deg, off);
    k_scatter<<<(N_EDGES + 255) / 256, 256, 0, stream>>>(row, col, ea, off, row_s, col_s, ea_s);
    k_packW2<<<N_LAYERS, 256, 0, stream>>>(ew2, W2p);

    k_embed<<<(N_NODES * HID + 255) / 256, 256, 0, stream>>>(nodes, emb_w, emb_b, h);

    const int gemm_grid = (N_NODES + 63) / 64;
    for (int l = 0; l < N_LAYERS; ++l) {
        const float* W1 = ew1 + (size_t)l * 257 * 128;
        k_gemm<<<gemm_grid, 256, 0, stream>>>(h, nullptr, W1, eb1 + l * 128, r1, N_NODES, 128, 0);
        k_gemm<<<gemm_grid, 256, 0, stream>>>(h, nullptr, W1 + 128 * 128, nullptr, other, N_NODES, 128, 0);
        hipMemsetAsync(r3, 0, NH * sizeof(float), stream);
        k_edge4<<<512, 512, 0, stream>>>(r1, other, W1 + 256 * 128, eb2 + l * 128,
                                         W2p + (size_t)l * 128 * 128, row_s, col_s, ea_s, r3);
        k_gemm<<<gemm_grid, 256, 0, stream>>>(h, r3, nw1 + (size_t)l * 256 * 128, nb1 + l * 128,
                                              r1, N_NODES, 256, 1);
        k_gemm<<<gemm_grid, 256, 0, stream>>>(r1, nullptr, nw2 + (size_t)l * 128 * 128, nb2 + l * 128,
                                              other, N_NODES, 128, 0);
        float* tmp = h; h = other; other = tmp;
    }
    k_gemm<<<gemm_grid, 256, 0, stream>>>(h, nullptr, dw1, db1, r1, N_NODES, 128, 1);
    k_dec2<<<(N_NODES + 255) / 256, 256, 0, stream>>>(r1, dw2, db2, (float*)d_out);
}

// Round 5
// 1009.290 us; speedup vs baseline: 9.3502x; 1.2132x over previous
//
#include <hip/hip_runtime.h>

#define N_NODES 50000
#define N_EDGES 640000
#define HID 128
#define N_LAYERS 4
#define TILE_E 128

typedef _Float16 f16x8 __attribute__((ext_vector_type(8)));
typedef float f32x16 __attribute__((ext_vector_type(16)));

__device__ __forceinline__ float silu_f(float x) {
    return x * __builtin_amdgcn_rcpf(1.0f + __expf(-x));
}

__device__ __forceinline__ f32x16 zero16() {
    f32x16 z;
#pragma unroll
    for (int i = 0; i < 16; ++i) z[i] = 0.f;
    return z;
}

// h[i,c] = sum_k nodes[i,k]*emb_w[k,c] + emb_b[c]
__global__ void k_embed(const float* __restrict__ nodes, const float* __restrict__ ew,
                        const float* __restrict__ eb, float* __restrict__ h) {
    int idx = blockIdx.x * 256 + threadIdx.x;
    if (idx >= N_NODES * HID) return;
    int i = idx >> 7, c = idx & 127;
    float n0 = nodes[i * 3 + 0], n1 = nodes[i * 3 + 1], n2 = nodes[i * 3 + 2];
    h[idx] = n0 * ew[c] + n1 * ew[HID + c] + n2 * ew[2 * HID + c] + eb[c];
}

// ---- counting sort of edges by row ----
__global__ void k_hist(const int* __restrict__ row, int* __restrict__ deg) {
    int e = blockIdx.x * 256 + threadIdx.x;
    if (e < N_EDGES) atomicAdd(&deg[row[e]], 1);
}

__global__ __launch_bounds__(1024) void k_scan(const int* __restrict__ deg, int* __restrict__ off) {
    __shared__ int partial[1024];
    const int t = threadIdx.x;
    const int chunk = (N_NODES + 1023) / 1024;
    const int base = t * chunk;
    int s = 0;
    for (int i = 0; i < chunk; ++i) {
        int idx = base + i;
        if (idx < N_NODES) s += deg[idx];
    }
    partial[t] = s;
    __syncthreads();
    for (int o = 1; o < 1024; o <<= 1) {
        int v = (t >= o) ? partial[t - o] : 0;
        __syncthreads();
        partial[t] += v;
        __syncthreads();
    }
    int run = (t == 0) ? 0 : partial[t - 1];
    for (int i = 0; i < chunk; ++i) {
        int idx = base + i;
        if (idx < N_NODES) {
            off[idx] = run;
            run += deg[idx];
        }
    }
}

__global__ void k_scatter(const int* __restrict__ row, const int* __restrict__ col,
                          const float* __restrict__ ea, int* __restrict__ off,
                          int* __restrict__ row_s, int* __restrict__ col_s,
                          float* __restrict__ ea_s) {
    int e = blockIdx.x * 256 + threadIdx.x;
    if (e >= N_EDGES) return;
    int r = row[e];
    int pos = atomicAdd(&off[r], 1);
    row_s[pos] = r;
    col_s[pos] = col[e];
    ea_s[pos] = ea[e];
}

// Pack W2[l] (128x128) into single-f16 B-frags for the edge kernel.
__global__ __launch_bounds__(256) void k_packW2(const float* __restrict__ W2all,
                                                _Float16* __restrict__ W2p) {
    const int layer = blockIdx.x;
    const float* W2 = W2all + (size_t)layer * 128 * 128;
    _Float16* out = W2p + (size_t)layer * 128 * 128;
    const int t = threadIdx.x;
    for (int fl = t; fl < 2048; fl += 256) {
        int blk = fl >> 6, lane = fl & 63;
        int cb = blk >> 3, kb = blk & 7;
        int colg = cb * 32 + (lane & 31);
        int kbase = kb * 16 + (lane >> 5) * 8;
        f16x8 v;
#pragma unroll
        for (int j = 0; j < 8; ++j)
            v[j] = (_Float16)W2[(size_t)(kbase + j) * 128 + colg];
        *(f16x8*)&out[(size_t)fl * 8] = v;
    }
}

// Pack node-MLP / decoder weights into hi/lo split-f16 B-frags.
// Layout: frag[t in {hi,lo}][ks][cb][lane][8]; lo prescaled by 2048.
__global__ __launch_bounds__(256) void k_packAll(
    const float* __restrict__ ew1, const float* __restrict__ nw1,
    const float* __restrict__ nw2, const float* __restrict__ dw1,
    _Float16* __restrict__ WpA, _Float16* __restrict__ WpB,
    _Float16* __restrict__ WpN1, _Float16* __restrict__ WpN2,
    _Float16* __restrict__ WpD1) {
    const int b = blockIdx.x;
    const float* W; _Float16* dst; int K16;
    if (b < 4)       { W = ew1 + (size_t)b * 257 * 128;              dst = WpA  + (size_t)b * 32768; K16 = 8; }
    else if (b < 8)  { int l = b - 4;  W = ew1 + (size_t)l * 257 * 128 + 128 * 128; dst = WpB + (size_t)l * 32768; K16 = 8; }
    else if (b < 12) { int l = b - 8;  W = nw1 + (size_t)l * 256 * 128; dst = WpN1 + (size_t)l * 65536; K16 = 16; }
    else if (b < 16) { int l = b - 12; W = nw2 + (size_t)l * 128 * 128; dst = WpN2 + (size_t)l * 32768; K16 = 8; }
    else             { W = dw1; dst = WpD1; K16 = 8; }
    for (int fl = threadIdx.x; fl < K16 * 256; fl += 256) {
        int lane = fl & 63, cb = (fl >> 6) & 3, ks = fl >> 8;
        int col = cb * 32 + (lane & 31);
        int kb = ks * 16 + (lane >> 5) * 8;
        f16x8 h8, l8;
#pragma unroll
        for (int j = 0; j < 8; ++j) {
            float wv = W[(size_t)(kb + j) * 128 + col];
            _Float16 hh = (_Float16)wv;
            h8[j] = hh;
            l8[j] = (_Float16)((wv - (float)hh) * 2048.0f);
        }
        *(f16x8*)&dst[((size_t)(0 * K16 + ks) * 4 + cb) * 512 + lane * 8] = h8;
        *(f16x8*)&dst[((size_t)(1 * K16 + ks) * 4 + cb) * 512 + lane * 8] = l8;
    }
}

// Split-f16 MFMA GEMM: out[M,128] = act(X[M,K]@W + bias), fp32-equivalent.
// No LDS: A-frags read straight from X (row-major, 8 contig floats/lane);
// B-frags from L2-resident packed weights. Dual mode: two weights sharing X.
__global__ __launch_bounds__(512) void k_gemm3(
    const float* __restrict__ X1, const float* __restrict__ X2,
    const _Float16* __restrict__ Wp0, const float* __restrict__ bias0, float* __restrict__ out0,
    const _Float16* __restrict__ Wp1, const float* __restrict__ bias1, float* __restrict__ out1,
    int M, int K16, int do_silu) {
    const int t = threadIdx.x, w = t >> 6, l = t & 63;
    const int lane31 = l & 31, hi = l >> 5;
    const bool dual = (Wp1 != nullptr);
    int rb, cb0, sel;
    if (dual) { rb = w & 1; sel = w >> 2; cb0 = ((w >> 1) & 1) * 2; }
    else      { rb = w & 3; sel = 0;      cb0 = (w >> 2) * 2; }
    const int mtile = dual ? 64 : 128;
    const int m0 = blockIdx.x * mtile;
    const _Float16* Wp = sel ? Wp1 : Wp0;
    const float* bias = sel ? bias1 : bias0;
    float* out = sel ? out1 : out0;

    int rowg = m0 + rb * 32 + lane31;
    if (rowg >= M) rowg = M - 1;
    const int koff = hi * 8;

    f32x16 aH0 = zero16(), aH1 = zero16(), aL0 = zero16(), aL1 = zero16();
    const f16x8* Wv = (const f16x8*)Wp;
#pragma unroll 4
    for (int ks = 0; ks < K16; ++ks) {
        const float* Xp = (X2 != nullptr && ks >= 8) ? X2 : X1;
        const float* px = &Xp[(size_t)rowg * 128 + (ks & 7) * 16 + koff];
        float xv[8];
        *(float4*)&xv[0] = *(const float4*)px;
        *(float4*)&xv[4] = *(const float4*)(px + 4);
        f16x8 xh, xl;
#pragma unroll
        for (int q = 0; q < 8; ++q) {
            _Float16 hh = (_Float16)xv[q];
            xh[q] = hh;
            xl[q] = (_Float16)((xv[q] - (float)hh) * 2048.0f);
        }
        f16x8 bh0 = Wv[((size_t)ks * 4 + cb0) * 64 + l];
        f16x8 bh1 = Wv[((size_t)ks * 4 + cb0 + 1) * 64 + l];
        f16x8 bl0 = Wv[((size_t)(K16 + ks) * 4 + cb0) * 64 + l];
        f16x8 bl1 = Wv[((size_t)(K16 + ks) * 4 + cb0 + 1) * 64 + l];
        aH0 = __builtin_amdgcn_mfma_f32_32x32x16_f16(xh, bh0, aH0, 0, 0, 0);
        aH1 = __builtin_amdgcn_mfma_f32_32x32x16_f16(xh, bh1, aH1, 0, 0, 0);
        aL0 = __builtin_amdgcn_mfma_f32_32x32x16_f16(xh, bl0, aL0, 0, 0, 0);
        aL0 = __builtin_amdgcn_mfma_f32_32x32x16_f16(xl, bh0, aL0, 0, 0, 0);
        aL1 = __builtin_amdgcn_mfma_f32_32x32x16_f16(xh, bl1, aL1, 0, 0, 0);
        aL1 = __builtin_amdgcn_mfma_f32_32x32x16_f16(xl, bh1, aL1, 0, 0, 0);
    }
    const float inv = 1.0f / 2048.0f;
#pragma unroll
    for (int c = 0; c < 2; ++c) {
        int col = (cb0 + c) * 32 + lane31;
        float bv = bias ? bias[col] : 0.f;
        const f32x16& aH = c ? aH1 : aH0;
        const f32x16& aL = c ? aL1 : aL0;
#pragma unroll
        for (int r = 0; r < 16; ++r) {
            int gr = m0 + rb * 32 + (r & 3) + 8 * (r >> 2) + 4 * hi;
            if (gr < M) {
                float v = aH[r] + aL[r] * inv + bv;
                out[(size_t)gr * 128 + col] = do_silu ? silu_f(v) : v;
            }
        }
    }
}

// Fused decoder: u = silu(h@dw1+db1) (split-f16 MFMA) -> LDS -> out = u@dw2+db2.
__global__ __launch_bounds__(512) void k_dec(
    const float* __restrict__ X, const _Float16* __restrict__ WpD,
    const float* __restrict__ db1, const float* __restrict__ dw2,
    const float* __restrict__ db2, float* __restrict__ out, int M) {
    __shared__ float u_lds[128 * 133];
    __shared__ float w2_lds[384];
    const int t = threadIdx.x, w = t >> 6, l = t & 63;
    const int lane31 = l & 31, hi = l >> 5;
    const int rb = w & 3, cb0 = (w >> 2) * 2;
    const int m0 = blockIdx.x * 128;
    if (t < 384) w2_lds[t] = dw2[t];

    int rowg = m0 + rb * 32 + lane31;
    if (rowg >= M) rowg = M - 1;
    const int koff = hi * 8;

    f32x16 aH0 = zero16(), aH1 = zero16(), aL0 = zero16(), aL1 = zero16();
    const f16x8* Wv = (const f16x8*)WpD;
#pragma unroll
    for (int ks = 0; ks < 8; ++ks) {
        const float* px = &X[(size_t)rowg * 128 + ks * 16 + koff];
        float xv[8];
        *(float4*)&xv[0] = *(const float4*)px;
        *(float4*)&xv[4] = *(const float4*)(px + 4);
        f16x8 xh, xl;
#pragma unroll
        for (int q = 0; q < 8; ++q) {
            _Float16 hh = (_Float16)xv[q];
            xh[q] = hh;
            xl[q] = (_Float16)((xv[q] - (float)hh) * 2048.0f);
        }
        f16x8 bh0 = Wv[((size_t)ks * 4 + cb0) * 64 + l];
        f16x8 bh1 = Wv[((size_t)ks * 4 + cb0 + 1) * 64 + l];
        f16x8 bl0 = Wv[((size_t)(8 + ks) * 4 + cb0) * 64 + l];
        f16x8 bl1 = Wv[((size_t)(8 + ks) * 4 + cb0 + 1) * 64 + l];
        aH0 = __builtin_amdgcn_mfma_f32_32x32x16_f16(xh, bh0, aH0, 0, 0, 0);
        aH1 = __builtin_amdgcn_mfma_f32_32x32x16_f16(xh, bh1, aH1, 0, 0, 0);
        aL0 = __builtin_amdgcn_mfma_f32_32x32x16_f16(xh, bl0, aL0, 0, 0, 0);
        aL0 = __builtin_amdgcn_mfma_f32_32x32x16_f16(xl, bh0, aL0, 0, 0, 0);
        aL1 = __builtin_amdgcn_mfma_f32_32x32x16_f16(xh, bl1, aL1, 0, 0, 0);
        aL1 = __builtin_amdgcn_mfma_f32_32x32x16_f16(xl, bh1, aL1, 0, 0, 0);
    }
    const float inv = 1.0f / 2048.0f;
#pragma unroll
    for (int c = 0; c < 2; ++c) {
        int col = (cb0 + c) * 32 + lane31;
        float bv = db1[col];
        const f32x16& aH = c ? aH1 : aH0;
        const f32x16& aL = c ? aL1 : aL0;
#pragma unroll
        for (int r = 0; r < 16; ++r) {
            int lr = rb * 32 + (r & 3) + 8 * (r >> 2) + 4 * hi;
            u_lds[lr * 133 + col] = silu_f(aH[r] + aL[r] * inv + bv);
        }
    }
    __syncthreads();
    if (t < 384) {
        int rowl = t & 127, j = t >> 7;
        int gm = m0 + rowl;
        if (gm < M) {
            float s = db2[j];
            for (int c = 0; c < 128; ++c)
                s += u_lds[rowl * 133 + c] * w2_lds[c * 3 + j];
            out[(size_t)gm * 3 + j] = s;
        }
    }
}

// Edge kernel v4 (unchanged from R4).
__global__ __launch_bounds__(512, 4) void k_edge4(
    const float* __restrict__ A, const float* __restrict__ Bm,
    const float* __restrict__ w1last, const float* __restrict__ b2,
    const _Float16* __restrict__ W2p, const int* __restrict__ row_s,
    const int* __restrict__ col_s, const float* __restrict__ ea_s,
    float* __restrict__ agg) {
    __shared__ __align__(16) _Float16 W2s[16384];
    __shared__ __align__(16) _Float16 m1f[TILE_E * 136];
    __shared__ int rows_sh[TILE_E];
    __shared__ int segs_sh[TILE_E + 2];
    __shared__ unsigned long long masks_sh[2];

    const int t = threadIdx.x;
    const int w = t >> 6, l = t & 63;
    const int lane31 = l & 31, hi = l >> 5;

    for (int i = t; i < 2048; i += 512)
        ((float4*)W2s)[i] = ((const float4*)W2p)[i];

    const int e_mine = (w >> 1) * 32 + lane31;
    const int kbase0 = (w & 1) * 64 + hi * 8;

    const int rb_g = w & 3;
    const int cb0 = (w >> 2) * 2, cb1 = cb0 + 1;
    const float b20 = b2[cb0 * 32 + lane31];
    const float b21 = b2[cb1 * 32 + lane31];

    const f16x8* m1v = (const f16x8*)m1f;
    const f16x8* w2v = (const f16x8*)W2s;
    _Float16* mo = m1f;

    const int n_tiles = N_EDGES / TILE_E;
    const int stride = gridDim.x;

    int r_pf = 0; float ea_pf = 0.f;
    float bpf[32];

    auto issue_pf = [&](int tile) {
        int eg = tile * TILE_E + e_mine;
        r_pf = row_s[eg];
        int c = col_s[eg];
        ea_pf = ea_s[eg];
        const float* Bp = Bm + (size_t)c * 128;
#pragma unroll
        for (int j = 0; j < 4; ++j) {
            int k0 = kbase0 + j * 16;
            *(float4*)&bpf[j * 8] = *(const float4*)&Bp[k0];
            *(float4*)&bpf[j * 8 + 4] = *(const float4*)&Bp[k0 + 4];
        }
    };

    int tile = blockIdx.x;
    if (tile < n_tiles) issue_pf(tile);

    for (; tile < n_tiles; tile += stride) {
        __syncthreads();

        {
            const int r = r_pf;
            const float eav = ea_pf;
            const float* Ap = A + (size_t)r * 128;
#pragma unroll
            for (int j = 0; j < 4; ++j) {
                int k0 = kbase0 + j * 16;
                float av[8], wv_[8];
                *(float4*)&av[0] = *(const float4*)&Ap[k0];
                *(float4*)&av[4] = *(const float4*)&Ap[k0 + 4];
                *(float4*)&wv_[0] = *(const float4*)&w1last[k0];
                *(float4*)&wv_[4] = *(const float4*)&w1last[k0 + 4];
                f16x8 o;
#pragma unroll
                for (int q = 0; q < 8; ++q)
                    o[q] = (_Float16)silu_f(av[q] + bpf[j * 8 + q] + eav * wv_[q]);
                *(f16x8*)&m1f[(w * 4 + j) * 512 + l * 8] = o;
            }
            if ((w & 1) == 0 && hi == 0) rows_sh[e_mine] = r;
        }
        __syncthreads();

        if (t < 128) {
            bool flag = (t == 0) || (rows_sh[t] != rows_sh[t - 1]);
            unsigned long long m = __ballot(flag);
            if ((t & 63) == 0) masks_sh[t >> 6] = m;
        }

        int nt = tile + stride;
        if (nt < n_tiles) issue_pf(nt);

        f32x16 acc0 = zero16(), acc1 = zero16();
#pragma unroll
        for (int kb = 0; kb < 8; ++kb) {
            f16x8 a = m1v[(rb_g * 8 + kb) * 64 + l];
            acc0 = __builtin_amdgcn_mfma_f32_32x32x16_f16(a, w2v[(cb0 * 8 + kb) * 64 + l], acc0, 0, 0, 0);
            acc1 = __builtin_amdgcn_mfma_f32_32x32x16_f16(a, w2v[(cb1 * 8 + kb) * 64 + l], acc1, 0, 0, 0);
        }
        __syncthreads();

        const unsigned long long m0 = masks_sh[0], m1m = masks_sh[1];
        const int ns = __popcll(m0) + __popcll(m1m);
        if (t < 128) {
            bool bit = (t < 64) ? ((m0 >> t) & 1ull) : ((m1m >> (t - 64)) & 1ull);
            if (bit) {
                int idx = (t < 64) ? __popcll(m0 & ((1ull << t) - 1))
                                   : __popcll(m0) + __popcll(m1m & ((1ull << (t - 64)) - 1));
                segs_sh[idx] = t;
            }
        }
        if (t == 0) segs_sh[ns] = TILE_E;

#pragma unroll
        for (int r = 0; r < 16; ++r) {
            int rowi = (r & 3) + 8 * (r >> 2) + 4 * hi;
            int erow = rb_g * 32 + rowi;
            mo[erow * 136 + cb0 * 32 + lane31] = (_Float16)silu_f(acc0[r] + b20);
            mo[erow * 136 + cb1 * 32 + lane31] = (_Float16)silu_f(acc1[r] + b21);
        }
        __syncthreads();

        {
            const int c = t & 127, g = t >> 7;
            for (int s = g; s < ns; s += 4) {
                int st = segs_sh[s], en = segs_sh[s + 1];
                float sum = 0.f;
                for (int q = st; q < en; ++q) sum += (float)mo[q * 136 + c];
                atomicAdd(&agg[(size_t)rows_sh[st] * 128 + c], sum);
            }
        }
    }
}

extern "C" void kernel_launch(void* const* d_in, const int* in_sizes, int n_in,
                              void* d_out, int out_size, void* d_ws, size_t ws_size,
                              hipStream_t stream) {
    const float* nodes = (const float*)d_in[0];
    const int* edges = (const int*)d_in[1];
    const float* ea = (const float*)d_in[2];
    const float* emb_w = (const float*)d_in[3];
    const float* emb_b = (const float*)d_in[4];
    const float* ew1 = (const float*)d_in[5];
    const float* eb1 = (const float*)d_in[6];
    const float* ew2 = (const float*)d_in[7];
    const float* eb2 = (const float*)d_in[8];
    const float* nw1 = (const float*)d_in[9];
    const float* nb1 = (const float*)d_in[10];
    const float* nw2 = (const float*)d_in[11];
    const float* nb2 = (const float*)d_in[12];
    const float* dw1 = (const float*)d_in[13];
    const float* db1 = (const float*)d_in[14];
    const float* dw2 = (const float*)d_in[15];
    const float* db2 = (const float*)d_in[16];
    const int* row = edges;
    const int* col = edges + N_EDGES;

    const size_t NH = (size_t)N_NODES * HID;
    float* r0 = (float*)d_ws;        // h
    float* r1 = r0 + NH;             // A / u
    float* r2 = r1 + NH;             // B / h_new
    float* r3 = r2 + NH;             // agg
    int* deg = (int*)(r3 + NH);
    int* off = deg + N_NODES;
    int* row_s = off + N_NODES;
    int* col_s = row_s + N_EDGES;
    float* ea_s = (float*)(col_s + N_EDGES);
    _Float16* W2p = (_Float16*)(ea_s + N_EDGES);
    _Float16* WpA  = W2p  + (size_t)4 * 16384;
    _Float16* WpB  = WpA  + (size_t)4 * 32768;
    _Float16* WpN1 = WpB  + (size_t)4 * 32768;
    _Float16* WpN2 = WpN1 + (size_t)4 * 65536;
    _Float16* WpD1 = WpN2 + (size_t)4 * 32768;

    float* h = r0;
    float* other = r2;

    // one-time: counting sort by row + weight pre-packs
    hipMemsetAsync(deg, 0, N_NODES * sizeof(int), stream);
    k_hist<<<(N_EDGES + 255) / 256, 256, 0, stream>>>(row, deg);
    k_scan<<<1, 1024, 0, stream>>>(deg, off);
    k_scatter<<<(N_EDGES + 255) / 256, 256, 0, stream>>>(row, col, ea, off, row_s, col_s, ea_s);
    k_packW2<<<N_LAYERS, 256, 0, stream>>>(ew2, W2p);
    k_packAll<<<17, 256, 0, stream>>>(ew1, nw1, nw2, dw1, WpA, WpB, WpN1, WpN2, WpD1);

    k_embed<<<(N_NODES * HID + 255) / 256, 256, 0, stream>>>(nodes, emb_w, emb_b, h);

    const int g128 = (N_NODES + 127) / 128;   // 391
    const int g64 = (N_NODES + 63) / 64;      // 782
    for (int l = 0; l < N_LAYERS; ++l) {
        const float* W1 = ew1 + (size_t)l * 257 * 128;
        // A = r1 = h@W1a + b1 ; B = other = h@W1b   (dual, shares h reads)
        k_gemm3<<<g64, 512, 0, stream>>>(h, nullptr,
                                         WpA + (size_t)l * 32768, eb1 + l * 128, r1,
                                         WpB + (size_t)l * 32768, nullptr, other,
                                         N_NODES, 8, 0);
        hipMemsetAsync(r3, 0, NH * sizeof(float), stream);
        k_edge4<<<512, 512, 0, stream>>>(r1, other, W1 + 256 * 128, eb2 + l * 128,
                                         W2p + (size_t)l * 128 * 128, row_s, col_s, ea_s, r3);
        // u = r1 = silu([h, agg] @ nw1 + nb1)
        k_gemm3<<<g128, 512, 0, stream>>>(h, r3,
                                          WpN1 + (size_t)l * 65536, nb1 + l * 128, r1,
                                          nullptr, nullptr, nullptr,
                                          N_NODES, 16, 1);
        // h_new = other = u @ nw2 + nb2
        k_gemm3<<<g128, 512, 0, stream>>>(r1, nullptr,
                                          WpN2 + (size_t)l * 32768, nb2 + l * 128, other,
                                          nullptr, nullptr, nullptr,
                                          N_NODES, 8, 0);
        float* tmp = h; h = other; other = tmp;
    }
    k_dec<<<g128, 512, 0, stream>>>(h, WpD1, db1, dw2, db2, (float*)d_out, N_NODES);
}